// Round 14
// baseline (944.130 us; speedup 1.0000x reference)
//
#include <hip/hip_runtime.h>
#include <cstdint>
#include <cstddef>

#define Bq 256
#define Tq 1024
#define Sq 7
#define Hq 64
#define Lq 4
#define OUTq 3
#define Uq 8                     // timesteps per barrier beat
#define NTB (Tq / Uq)            // 128 work-beats per wave
#define NBEATS (NTB + Lq - 1)    // 131 total beats (pipeline fill)

typedef float vf16 __attribute__((ext_vector_type(16)));
typedef float vf4 __attribute__((ext_vector_type(4)));

// Scalar-side bit test (SALU pipe): s_bitcmp1 + s_cselect produce f in
// {0.0f,1.0f}, leaving ONE VALU op per weight element (v_fmac, SGPR src0).
template<int BIT>
__device__ __forceinline__ float selbit(unsigned ws) {
    float f;
    asm("s_bitcmp1_b32 %1, %2\n\ts_cselect_b32 %0, 1.0, 0"
        : "=s"(f) : "s"(ws), "i"(BIT) : "scc");
    return f;
}

__device__ __forceinline__ void sfmac(float& a, float f, float w) {
    asm("v_fmac_f32 %0, %1, %2" : "+v"(a) : "s"(f), "v"(w));
}

// Systolic SNN scan, U=8 timesteps per beat, 131 barriers total.
// v3 change: the heavy-wave (layers 1..3) timestep loop is ROLLED
// (#pragma unroll 1). v2's fully-unrolled beat body was ~2240 instructions
// (~18-20 KB) -> thrashed the 32 KB L1I every beat (measured ~7500 cyc/beat
// stall with zero data-memory pressure). Rolled body is ~215 inst (~1.7 KB),
// I$-resident. Spike masks are re-read per timestep from LDS with a
// one-iteration software prefetch (ds_read_b64 issued before the ~1.1k-cycle
// compute). Ballot results are written to LDS per timestep by lane 0
// (no runtime-indexed register array -> no scratch). Wave 0 stays fully
// unrolled (small body; keeps xcur[] compile-time indexed).
// Numerics: identical per-element op order to the passing kernels ->
// bit-identical results.
__global__ __launch_bounds__(256, 1) void snn_seq_kernel(
    const float* __restrict__ x,       // (B,T,S)
    const float* __restrict__ hs_in,   // (B,T,L,H)
    const float* __restrict__ w1,      // (H,S)
    const float* __restrict__ b1,      // (H)
    const float* __restrict__ w_h,     // (L-1,H,H)
    const float* __restrict__ b_h,     // (L-1,H)
    float* __restrict__ out_mem)       // (B,T,L,H)
{
    __shared__ __align__(16) unsigned long long lmask[2][Lq][Uq]; // [slot][producer layer][i]

    const int b = blockIdx.x;
    const int lane = threadIdx.x & 63;
    const int wv = threadIdx.x >> 6;   // 0..3 = layer index

    // membrane state for this wave's layer, init from hidden_states[:,0]
    float m = hs_in[(((size_t)b * Tq) * Lq + wv) * Hq + lane];
    float* omem = out_mem + ((size_t)b * Tq * Lq + wv) * Hq + lane;

    // wave-0 (input projection) state
    float w1r[Sq];
    float b1r = 0.0f;
    const float* xrow = x + (size_t)b * Tq * Sq;
    vf4 xcur[14];                      // current beat's 8 x-rows (56 floats)
    // waves 1..3 (recurrent) state: 64 weight floats in registers
    vf16 W0, W1, W2, W3;
    float bhr = 0.0f;

    if (wv == 0) {
#pragma unroll
        for (int s = 0; s < Sq; ++s) w1r[s] = w1[lane * Sq + s];
        b1r = b1[lane];
        const vf4* xp4 = (const vf4*)xrow;   // beat 0 rows (uniform broadcast loads)
#pragma unroll
        for (int i = 0; i < 14; ++i) xcur[i] = xp4[i];
    } else {
        const vf16* wr = (const vf16*)(w_h + ((size_t)((wv - 1) * Hq + lane)) * Hq);
        W0 = wr[0]; W1 = wr[1]; W2 = wr[2]; W3 = wr[3];
        bhr = b_h[(wv - 1) * Hq + lane];
    }

#define XC(e) xcur[(e) >> 2][(e) & 3]

    // 4 elements (one q-group) of one 16-wide block; BASE/QQ are literals so
    // the selbit<> template arg is a compile-time constant.
#define DOQ(Wv, ws, BASE, QQ)                                        \
    {                                                                \
        float f0 = selbit<(BASE) + 4 * (QQ) + 0>(ws);                \
        float f1 = selbit<(BASE) + 4 * (QQ) + 1>(ws);                \
        float f2 = selbit<(BASE) + 4 * (QQ) + 2>(ws);                \
        float f3 = selbit<(BASE) + 4 * (QQ) + 3>(ws);                \
        sfmac(a0, f0, Wv[4 * (QQ) + 0]);                             \
        sfmac(a1, f1, Wv[4 * (QQ) + 1]);                             \
        sfmac(a2, f2, Wv[4 * (QQ) + 2]);                             \
        sfmac(a3, f3, Wv[4 * (QQ) + 3]);                             \
    }
#define DOBLK(Wv, ws, BASE)                                          \
    DOQ(Wv, ws, BASE, 0) DOQ(Wv, ws, BASE, 1)                        \
    DOQ(Wv, ws, BASE, 2) DOQ(Wv, ws, BASE, 3)

#pragma unroll 1
    for (int k = 0; k < NBEATS; ++k) {
        if (wv == 0) {
            if (k < NTB) {
                // prefetch next beat's 8 x-rows (latency spans this beat's compute)
                const int kp = (k < NTB - 1) ? k + 1 : k;
                const vf4* xp4 = (const vf4*)(xrow + (size_t)kp * (Uq * Sq));
                vf4 xn[14];
#pragma unroll
                for (int i = 0; i < 14; ++i) xn[i] = xp4[i];

                unsigned long long produced[Uq];
#pragma unroll
                for (int i = 0; i < Uq; ++i) {
                    float cur = b1r;
#pragma unroll
                    for (int s = 0; s < Sq; ++s) cur = fmaf(XC(i * Sq + s), w1r[s], cur);
                    float rst = (m > 1.0f) ? 1.0f : 0.0f;
                    float mn = __fadd_rn(__fmul_rn(0.8f, m), cur);
                    mn = __fsub_rn(mn, rst);
                    m = mn;
                    omem[(size_t)(k * Uq + i) * (Lq * Hq)] = mn;  // fire-and-forget
                    produced[i] = __ballot(mn > 1.0f);
                }
                if (lane == 0) {
#pragma unroll
                    for (int i = 0; i < Uq; ++i) lmask[k & 1][0][i] = produced[i];
                }
#pragma unroll
                for (int i = 0; i < 14; ++i) xcur[i] = xn[i];
            }
        } else {
            const int tt = k - wv;
            if (tt >= 0 && tt < NTB) {
                // rolled timestep loop (I$-resident body), one-ahead mask prefetch
                const unsigned long long* mrow = &lmask[(k - 1) & 1][wv - 1][0];
                float* op = omem + (size_t)tt * Uq * (Lq * Hq);
                uint2 mr = *(const uint2*)&mrow[0];   // mask[0]
#pragma unroll 1
                for (int i = 0; i < Uq; ++i) {
                    unsigned lo = (unsigned)__builtin_amdgcn_readfirstlane((int)mr.x);
                    unsigned hi = (unsigned)__builtin_amdgcn_readfirstlane((int)mr.y);
                    // prefetch mask[i+1] (i=7 re-reads [0]; harmless)
                    uint2 mr_n = *(const uint2*)&mrow[(i + 1) & (Uq - 1)];

                    float a0 = bhr, a1 = 0.0f, a2 = 0.0f, a3 = 0.0f;
                    DOBLK(W0, lo, 0)
                    DOBLK(W1, lo, 16)
                    DOBLK(W2, hi, 0)
                    DOBLK(W3, hi, 16)
                    float cur = __fadd_rn(__fadd_rn(a0, a1), __fadd_rn(a2, a3));

                    float rst = (m > 1.0f) ? 1.0f : 0.0f;
                    float mn = __fadd_rn(__fmul_rn(0.8f, m), cur);
                    mn = __fsub_rn(mn, rst);
                    m = mn;
                    op[(size_t)i * (Lq * Hq)] = mn;   // fire-and-forget

                    if (wv < Lq - 1) {
                        unsigned long long msk = __ballot(mn > 1.0f);
                        if (lane == 0) lmask[k & 1][wv][i] = msk;
                    }
                    mr = mr_n;
                }
            }
        }
        // beat barrier: drain LDS (mask handoff) but NOT vmem stores
        asm volatile("s_waitcnt lgkmcnt(0)\n\ts_barrier" ::: "memory");
    }
#undef DOBLK
#undef DOQ
#undef XC
}

// Readout deferred out of the sequential path: recompute layer-3 spikes from
// the stored membrane states. 16 lanes per (b,t) row.
__global__ __launch_bounds__(256) void snn_out_kernel(
    const float* __restrict__ mem,    // (B,T,L,H)
    const float* __restrict__ w_out,  // (OUT,H)
    const float* __restrict__ b_out,  // (OUT)
    float* __restrict__ out0)         // (B,T,OUT)
{
    const long long idx = (long long)blockIdx.x * 16 + (threadIdx.x >> 4); // b*T + t
    const int sub = threadIdx.x & 15;
    if (idx >= (long long)Bq * Tq) return;

    float4 mv = ((const float4*)mem)[(size_t)idx * 64 + 48 + sub];
    float4 s;
    s.x = (mv.x > 1.0f) ? 1.0f : 0.0f;
    s.y = (mv.y > 1.0f) ? 1.0f : 0.0f;
    s.z = (mv.z > 1.0f) ? 1.0f : 0.0f;
    s.w = (mv.w > 1.0f) ? 1.0f : 0.0f;

#pragma unroll
    for (int o = 0; o < OUTq; ++o) {
        float4 wv = ((const float4*)w_out)[o * 16 + sub];
        float v = s.x * wv.x + s.y * wv.y + s.z * wv.z + s.w * wv.w;
#pragma unroll
        for (int off = 8; off > 0; off >>= 1) v += __shfl_xor(v, off, 16);
        if (sub == 0) out0[idx * OUTq + o] = v + b_out[o];
    }
}

__global__ __launch_bounds__(256) void copy_x_kernel(
    const float4* __restrict__ src, float4* __restrict__ dst, int n4)
{
    int i = blockIdx.x * 256 + threadIdx.x;
    if (i < n4) dst[i] = src[i];
}

extern "C" void kernel_launch(void* const* d_in, const int* in_sizes, int n_in,
                              void* d_out, int out_size, void* d_ws, size_t ws_size,
                              hipStream_t stream) {
    const float* x     = (const float*)d_in[0];
    const float* hs_in = (const float*)d_in[1];
    // d_in[2] = prev_obs (unused by reference)
    const float* w1    = (const float*)d_in[3];
    const float* b1    = (const float*)d_in[4];
    const float* w_h   = (const float*)d_in[5];
    const float* b_h   = (const float*)d_in[6];
    const float* w_out = (const float*)d_in[7];
    const float* b_out = (const float*)d_in[8];

    float* out0 = (float*)d_out;                                   // (B,T,OUT)
    float* out1 = out0 + (size_t)Bq * Tq * OUTq;                   // (B,T,L,H)
    float* out2 = out1 + (size_t)Bq * Tq * Lq * Hq;                // (B,T,S) = x

    // 1) systolic sequential SNN scan: writes new_hidden_states
    snn_seq_kernel<<<Bq, 256, 0, stream>>>(x, hs_in, w1, b1, w_h, b_h, out1);

    // 2) readout from stored layer-3 membranes
    const long long nbt = (long long)Bq * Tq;
    snn_out_kernel<<<(int)(nbt / 16), 256, 0, stream>>>(out1, w_out, b_out, out0);

    // 3) passthrough copy of x
    const int n4 = Bq * Tq * Sq / 4;
    copy_x_kernel<<<(n4 + 255) / 256, 256, 0, stream>>>((const float4*)x, (float4*)out2, n4);
}